// Round 11
// baseline (143.082 us; speedup 1.0000x reference)
//
#include <hip/hip_runtime.h>
#include <stdint.h>
#include <stddef.h>

// Causal attention fused layer for MI355X (gfx950).
// B=2 T=2048 C=1024 H=16 D=64.
// Pipeline: cvt x -> bf16 | transpose-cvt weights -> bf16 N*K | fused QKV GEMM (1 dispatch)
//           | V transpose (B,H,D,T) | flash attention (BARRIER-FREE: fully independent waves,
//             wave-private dbuf LDS 32-kv tiles, counted vmcnt, swizzled ds_read, swapped QK^T,
//             in-register softmax; per-block strip pairing -> uniform work) | out GEMM f32.
// Workspace layout (needs >= 48 MB):
//   [0,8MB)   x bf16            (M=4096 x K=1024)
//   [8,16MB)  Wt q,k,v,o bf16   (4 x 1024x1024, transposed N x K)
//   [16,32MB) Q,K bf16          ((B,H,T,D)), Q pre-scaled by 0.125*log2(e)
//   [32,40MB) V^T bf16          ((B,H,D,T))
//   [40,48MB) Vtmp then O bf16  (V normal layout, overwritten by attn output (B,T,C))

#define B_SZ 2
#define T_SZ 2048
#define C_SZ 1024
#define H_SZ 16
#define D_SZ 64
#define M_SZ (B_SZ * T_SZ)              // 4096
#define BHTD (B_SZ * H_SZ * T_SZ * D_SZ) // 4194304
#define CC (C_SZ * C_SZ)                 // 1048576

typedef __attribute__((ext_vector_type(8))) __bf16 bf16x8;
typedef __attribute__((ext_vector_type(4))) float f32x4;
typedef __attribute__((ext_vector_type(16))) float f32x16;

__device__ __forceinline__ unsigned short f2bf(float f) {
    union { float f; unsigned u; } v; v.f = f;
    v.u += 0x7fffu + ((v.u >> 16) & 1u);   // round-to-nearest-even
    return (unsigned short)(v.u >> 16);
}

__device__ __forceinline__ unsigned pkbf(float lo, float hi_) {
    union { unsigned u; __bf16 h[2]; } r;
    r.h[0] = (__bf16)lo; r.h[1] = (__bf16)hi_;    // compiler emits v_cvt_pk_bf16_f32
    return r.u;
}

__device__ __forceinline__ void load_lds16(const unsigned short* g, unsigned short* l) {
    __builtin_amdgcn_global_load_lds(
        (const __attribute__((address_space(1))) void*)g,
        (__attribute__((address_space(3))) void*)l, 16, 0, 0);
}

// ---------------- conversion kernels ----------------

__global__ void cvt_x_kernel(const float4* __restrict__ in, ushort4* __restrict__ out, int n4) {
    int stride = gridDim.x * blockDim.x;
    for (int i = blockIdx.x * blockDim.x + threadIdx.x; i < n4; i += stride) {
        float4 v = in[i];
        ushort4 o;
        o.x = f2bf(v.x); o.y = f2bf(v.y); o.z = f2bf(v.z); o.w = f2bf(v.w);
        out[i] = o;
    }
}

__global__ __launch_bounds__(256) void transpose_cvt_kernel(
    const float* __restrict__ W0, const float* __restrict__ W1,
    const float* __restrict__ W2, const float* __restrict__ W3,
    unsigned short* __restrict__ T0, unsigned short* __restrict__ T1,
    unsigned short* __restrict__ T2, unsigned short* __restrict__ T3)
{
    __shared__ float tile[32][33];
    const float* W; unsigned short* Wt;
    switch (blockIdx.z) {
        case 0: W = W0; Wt = T0; break;
        case 1: W = W1; Wt = T1; break;
        case 2: W = W2; Wt = T2; break;
        default: W = W3; Wt = T3; break;
    }
    const int tx = threadIdx.x, ty = threadIdx.y;     // 32 x 8
    const int n0 = blockIdx.x * 32, k0 = blockIdx.y * 32;
    #pragma unroll
    for (int i = 0; i < 4; i++)
        tile[ty + i * 8][tx] = W[(size_t)(k0 + ty + i * 8) * C_SZ + n0 + tx];
    __syncthreads();
    #pragma unroll
    for (int i = 0; i < 4; i++)
        Wt[(size_t)(n0 + ty + i * 8) * C_SZ + k0 + tx] = f2bf(tile[tx][ty + i * 8]);
}

// V (B,H,T,D) -> V^T (B,H,D,T), per-head 2048x64 transpose in 32x32 tiles.
__global__ __launch_bounds__(256) void vt_kernel(
    const unsigned short* __restrict__ V, unsigned short* __restrict__ Vt)
{
    __shared__ unsigned short tile[32][33];
    const int bh = blockIdx.z;
    const int t0 = blockIdx.x * 32, d0 = blockIdx.y * 32;
    const unsigned short* src = V + (size_t)bh * T_SZ * D_SZ;
    unsigned short* dst = Vt + (size_t)bh * T_SZ * D_SZ;
    const int tx = threadIdx.x, ty = threadIdx.y;     // 32 x 8
    #pragma unroll
    for (int i = 0; i < 4; i++)
        tile[ty + i * 8][tx] = src[(size_t)(t0 + ty + i * 8) * D_SZ + d0 + tx];
    __syncthreads();
    #pragma unroll
    for (int i = 0; i < 4; i++)
        dst[(size_t)(d0 + ty + i * 8) * T_SZ + t0 + tx] = tile[tx][ty + i * 8];
}

// ---------------- GEMM core (m97 structure: 128x128 tile, BK=32) ----------------

__device__ __forceinline__ void gemm_tile_core(
    const unsigned short* __restrict__ A,
    const unsigned short* __restrict__ Bt,
    unsigned short* As, unsigned short* Bs,
    int m0, int n0, f32x4 acc[4][4])
{
    const int tid = threadIdx.x;
    const int lane = tid & 63;
    const int w = tid >> 6;
    const int l15 = lane & 15, lg = lane >> 4;
    const int wr = (w >> 1) * 64, wc = (w & 1) * 64;

    const unsigned short* Ag0 = A + (size_t)(m0 + (tid >> 2)) * C_SZ + (tid & 3) * 8;
    const unsigned short* Ag1 = Ag0 + (size_t)64 * C_SZ;
    const unsigned short* Bg0 = Bt + (size_t)(n0 + (tid >> 2)) * C_SZ + (tid & 3) * 8;
    const unsigned short* Bg1 = Bg0 + (size_t)64 * C_SZ;
    unsigned short* As0 = As + w * 512;
    unsigned short* As1 = As + 2048 + w * 512;
    unsigned short* Bs0 = Bs + w * 512;
    unsigned short* Bs1 = Bs + 2048 + w * 512;

    for (int k0 = 0; k0 < C_SZ; k0 += 32) {
        load_lds16(Ag0 + k0, As0);
        load_lds16(Ag1 + k0, As1);
        load_lds16(Bg0 + k0, Bs0);
        load_lds16(Bg1 + k0, Bs1);
        __syncthreads();
        bf16x8 af[4], bfv[4];
        const bf16x8* Ap = (const bf16x8*)As;
        const bf16x8* Bp = (const bf16x8*)Bs;
        #pragma unroll
        for (int m = 0; m < 4; m++) af[m] = Ap[(wr + m * 16 + l15) * 4 + lg];
        #pragma unroll
        for (int n = 0; n < 4; n++) bfv[n] = Bp[(wc + n * 16 + l15) * 4 + lg];
        #pragma unroll
        for (int m = 0; m < 4; m++)
            #pragma unroll
            for (int n = 0; n < 4; n++)
                acc[m][n] = __builtin_amdgcn_mfma_f32_16x16x32_bf16(af[m], bfv[n], acc[m][n], 0, 0, 0);
        __syncthreads();
    }
}

// Fused QKV projection GEMM: ONE dispatch, grid (24, 32); z = blockIdx.x>>3 selects Q/K/V,
// n0 = (blockIdx.x&7)*128. Q,K -> (B,H,T,D) bf16 (Q scaled by 0.125*log2(e)); V -> Vtmp.
__global__ __launch_bounds__(256) void gemm_qkv_kernel(
    const unsigned short* __restrict__ A,
    const unsigned short* __restrict__ WtBase,
    const float* __restrict__ bq, const float* __restrict__ bk, const float* __restrict__ bv,
    unsigned short* __restrict__ QKV, unsigned short* __restrict__ Vtmp)
{
    __shared__ unsigned short As[4096], Bs[4096];
    const int z = blockIdx.x >> 3;
    const unsigned short* Bt = WtBase + (size_t)z * CC;
    const float* bias = (z == 0) ? bq : (z == 1) ? bk : bv;
    const float scale = (z == 0) ? 0.18033688011112042f : 1.0f;  // 0.125 * log2(e)
    unsigned short* Out = (z == 2) ? Vtmp : QKV + (size_t)z * BHTD;

    f32x4 acc[4][4];
    f32x4 zero4 = {0.f, 0.f, 0.f, 0.f};
    #pragma unroll
    for (int m = 0; m < 4; m++)
        #pragma unroll
        for (int n = 0; n < 4; n++) acc[m][n] = zero4;

    const int m0 = blockIdx.y * 128, n0 = (blockIdx.x & 7) * 128;
    gemm_tile_core(A, Bt, As, Bs, m0, n0, acc);

    const int lane = threadIdx.x & 63;
    const int w = threadIdx.x >> 6;
    const int l15 = lane & 15, lg = lane >> 4;
    const int wr = (w >> 1) * 64, wc = (w & 1) * 64;
    #pragma unroll
    for (int n = 0; n < 4; n++) {
        const int col = n0 + wc + n * 16 + l15;
        const float bias_v = bias[col];
        const int h = col >> 6, d = col & 63;
        #pragma unroll
        for (int m = 0; m < 4; m++) {
            #pragma unroll
            for (int j = 0; j < 4; j++) {
                const int row = m0 + wr + m * 16 + lg * 4 + j;   // global M row = b*T + t
                const int b = row >> 11, t = row & (T_SZ - 1);
                Out[(((size_t)(b * H_SZ + h)) * T_SZ + t) * D_SZ + d] =
                    f2bf((acc[m][n][j] + bias_v) * scale);
            }
        }
    }
}

// Output projection GEMM: 64x128 tiles (grid 8 x 64 = 512 blocks -> 2 blocks/CU).
__global__ __launch_bounds__(256) void gemm_out_kernel(
    const unsigned short* __restrict__ A,
    const unsigned short* __restrict__ Bt,
    const float* __restrict__ bo,
    float* __restrict__ Out)
{
    __shared__ unsigned short As[2048], Bs[4096];
    const int tid = threadIdx.x;
    const int lane = tid & 63;
    const int w = tid >> 6;
    const int l15 = lane & 15, lg = lane >> 4;
    const int wc = w * 32;
    const int m0 = blockIdx.y * 64, n0 = blockIdx.x * 128;

    const unsigned short* Ag  = A + (size_t)(m0 + (tid >> 2)) * C_SZ + (tid & 3) * 8;
    const unsigned short* Bg0 = Bt + (size_t)(n0 + (tid >> 2)) * C_SZ + (tid & 3) * 8;
    const unsigned short* Bg1 = Bg0 + (size_t)64 * C_SZ;
    unsigned short* As0 = As + w * 512;
    unsigned short* Bs0 = Bs + w * 512;
    unsigned short* Bs1 = Bs + 2048 + w * 512;

    f32x4 acc[4][2];
    f32x4 zero4 = {0.f, 0.f, 0.f, 0.f};
    #pragma unroll
    for (int m = 0; m < 4; m++)
        #pragma unroll
        for (int n = 0; n < 2; n++) acc[m][n] = zero4;

    for (int k0 = 0; k0 < C_SZ; k0 += 32) {
        load_lds16(Ag + k0, As0);
        load_lds16(Bg0 + k0, Bs0);
        load_lds16(Bg1 + k0, Bs1);
        __syncthreads();
        bf16x8 af[4], bfv[2];
        const bf16x8* Ap = (const bf16x8*)As;
        const bf16x8* Bp = (const bf16x8*)Bs;
        #pragma unroll
        for (int m = 0; m < 4; m++) af[m] = Ap[(m * 16 + l15) * 4 + lg];
        #pragma unroll
        for (int n = 0; n < 2; n++) bfv[n] = Bp[(wc + n * 16 + l15) * 4 + lg];
        #pragma unroll
        for (int m = 0; m < 4; m++)
            #pragma unroll
            for (int n = 0; n < 2; n++)
                acc[m][n] = __builtin_amdgcn_mfma_f32_16x16x32_bf16(af[m], bfv[n], acc[m][n], 0, 0, 0);
        __syncthreads();
    }

    #pragma unroll
    for (int n = 0; n < 2; n++) {
        const int col = n0 + wc + n * 16 + l15;
        const float bias_v = bo[col];
        #pragma unroll
        for (int m = 0; m < 4; m++) {
            #pragma unroll
            for (int j = 0; j < 4; j++) {
                const int row = m0 + m * 16 + lg * 4 + j;
                Out[(size_t)row * C_SZ + col] = acc[m][n][j] + bias_v;
            }
        }
    }
}

// ---------------- flash attention (barrier-free independent waves) ----------------
// grid 512 x 256thr. Block i: bh = i&31, p = i>>5 (0..15). Wave w owns q-strip
// qs = {2p, 63-2p, 2p+1, 62-2p}[w] (32 q rows at qw = 32*qs) -> per-block work = 130
// tiles, CONSTANT across all blocks (deterministic balance, no assignment assumption).
// Each wave double-buffers its own 32-kv K/V^T tiles in a PRIVATE 16KB LDS slice
// (4x16KB = 64KB/block -> 2 blocks/CU = 8 free-running waves/CU). Main loop has NO
// barriers: stage(t+1) -> s_waitcnt vmcnt(8) -> compute(t). K staged with pre-swizzled
// source slot^(row&7) (8 slots/row); V^T with slot^(d&3) (4 slots/row); ds_read applies
// the same XOR. Math (R3-verified): S^T = mfma(K,Q) 32x32x16 (C/D: col=lane&31,
// row=(r&3)+8*(r>>2)+4*(lane>>5)); in-register softmax at q=l31; P^T via cvt_pk +
// v_permlane32_swap_b32; O^T += mfma(V^T, P^T); deferred-rescale THR=8 (log2 units).
__global__ __launch_bounds__(256) void attn_fwd_kernel(
    const unsigned short* __restrict__ Q,
    const unsigned short* __restrict__ K,
    const unsigned short* __restrict__ Vt,
    unsigned short* __restrict__ O)
{
    const int i = blockIdx.x;
    const int bh = i & 31;
    const int p = i >> 5;                           // 0..15
    const int w = threadIdx.x >> 6;
    const int lane = threadIdx.x & 63;
    const int l31 = lane & 31, hi = lane >> 5;
    const int qs = (w == 0) ? 2 * p : (w == 1) ? 63 - 2 * p
                 : (w == 2) ? 2 * p + 1 : 62 - 2 * p;
    const int qw = qs * 32;

    const unsigned short* Qh = Q + (size_t)bh * T_SZ * D_SZ;
    const unsigned short* Kh = K + (size_t)bh * T_SZ * D_SZ;
    const unsigned short* Vh = Vt + (size_t)bh * T_SZ * D_SZ;   // (D,T) layout

    __shared__ __align__(16) unsigned short smem[32768];        // 64KB; wave w owns [w*8192, +8192)
    unsigned short* wb = smem + w * 8192;   // buf b at wb + b*4096: K [0,2048), V^T [2048,4096)

    // staging source offsets (pre-swizzled). K tile: 32 rows x 64 ushorts (8 chunks of 16B/row);
    // op ii covers chunks ii*64+lane: row = ii*8 + (lane>>3), slot = lane&7,
    // src slot' = slot ^ (row&7) = (lane&7)^(lane>>3) (row&7 == lane>>3, invariant in ii).
    const int koffb = (lane >> 3) * 64 + (((lane & 7) ^ (lane >> 3)) * 8);
    // V^T tile: 64 rows(d) x 32 ushorts (4 chunks/row); op ii covers chunks ii*64+lane:
    // d = ii*16 + (lane>>2), slot = lane&3, src slot' = slot ^ (d&3) = (lane&3)^((lane>>2)&3).
    const int voffb = (lane >> 2) * T_SZ + (((lane & 3) ^ ((lane >> 2) & 3)) * 8);

    // Q B-frags: q = qw + l31, k-chunks j*16 + 8*hi
    bf16x8 qf[4];
    #pragma unroll
    for (int j = 0; j < 4; j++)
        qf[j] = *(const bf16x8*)&Qh[(size_t)(qw + l31) * D_SZ + j * 16 + 8 * hi];

    f32x16 acc[2];                 // O^T: d-tiles 0/1, q=l31 cols
    #pragma unroll
    for (int r = 0; r < 16; r++) { acc[0][r] = 0.f; acc[1][r] = 0.f; }
    float mrun = -3.0e38f, lrun = 0.f;

    const int ntb = qs + 1;
    const int sw7 = l31 & 7, sw3 = l31 & 3;

    // ---- prologue: stage tile 0 into buffer 0 (8 wave-private loads) ----
    #pragma unroll
    for (int ii = 0; ii < 4; ii++)
        load_lds16(Kh + ii * 512 + koffb, wb + ii * 512);
    #pragma unroll
    for (int ii = 0; ii < 4; ii++)
        load_lds16(Vh + ii * 16 * T_SZ + voffb, wb + 2048 + ii * 512);

    for (int tt = 0; tt < ntb; ++tt) {
        // ---- issue next tile's staging (wave-private), wait only for tile tt's loads ----
        if (tt + 1 < ntb) {
            unsigned short* bd = wb + ((tt + 1) & 1) * 4096;
            const unsigned short* Kt = Kh + (size_t)(tt + 1) * 32 * D_SZ;
            const unsigned short* Vn = Vh + (tt + 1) * 32;
            #pragma unroll
            for (int ii = 0; ii < 4; ii++)
                load_lds16(Kt + ii * 512 + koffb, bd + ii * 512);
            #pragma unroll
            for (int ii = 0; ii < 4; ii++)
                load_lds16(Vn + ii * 16 * T_SZ + voffb, bd + 2048 + ii * 512);
            asm volatile("s_waitcnt vmcnt(8)" ::: "memory");
        } else {
            asm volatile("s_waitcnt vmcnt(0)" ::: "memory");
        }

        const unsigned short* Ks = wb + (tt & 1) * 4096;
        const unsigned short* Vs = Ks + 2048;

        // ---- S^T = K Q^T (32kv x 32q) over D=64 ----
        bf16x8 kf[4];
        #pragma unroll
        for (int j = 0; j < 4; ++j) {
            const int ch = (j * 2 + hi) ^ sw7;
            kf[j] = *(const bf16x8*)&Ks[l31 * 64 + ch * 8];
        }
        f32x16 s;
        #pragma unroll
        for (int r = 0; r < 16; r++) s[r] = 0.f;
        #pragma unroll
        for (int j = 0; j < 4; ++j)
            s = __builtin_amdgcn_mfma_f32_32x32x16_bf16(kf[j], qf[j], s, 0, 0, 0);

        // ---- causal mask (diagonal tile only: k0 == qw) ----
        if (tt == ntb - 1) {
            #pragma unroll
            for (int r = 0; r < 16; r++) {
                const int kvl = (r & 3) + 8 * (r >> 2) + 4 * hi;
                s[r] = (kvl > l31) ? -3.0e38f : s[r];
            }
        }

        // ---- row max (tree depth 4 + cross-half) ----
        float t8[8];
        #pragma unroll
        for (int k = 0; k < 8; k++) t8[k] = fmaxf(s[k], s[k + 8]);
        #pragma unroll
        for (int st = 4; st >= 1; st >>= 1)
            #pragma unroll
            for (int k = 0; k < st; k++) t8[k] = fmaxf(t8[k], t8[k + st]);
        const float pm = fmaxf(t8[0], __shfl_xor(t8[0], 32));

        // ---- deferred-rescale (T13, THR=8 in log2 units) ----
        if (!__all(pm <= mrun + 8.0f)) {
            const float mnew = fmaxf(mrun, pm);
            const float al = exp2f(mrun - mnew);
            lrun *= al;
            #pragma unroll
            for (int r = 0; r < 16; r++) { acc[0][r] *= al; acc[1][r] *= al; }
            mrun = mnew;
        }

        // ---- P = exp2(s - m); row sum (tree) ----
        #pragma unroll
        for (int r = 0; r < 16; r++) s[r] = exp2f(s[r] - mrun);
        float a8[8];
        #pragma unroll
        for (int k = 0; k < 8; k++) a8[k] = s[k] + s[k + 8];
        #pragma unroll
        for (int st = 4; st >= 1; st >>= 1)
            #pragma unroll
            for (int k = 0; k < st; k++) a8[k] += a8[k + st];
        lrun += a8[0] + __shfl_xor(a8[0], 32);

        // ---- pack P -> P^T B-frags via cvt_pk + permlane32_swap (2 k-steps of 16 kv) ----
        bf16x8 pf[2];
        #pragma unroll
        for (int ks = 0; ks < 2; ++ks) {
            unsigned a0 = pkbf(s[8 * ks + 0], s[8 * ks + 1]);
            unsigned a1 = pkbf(s[8 * ks + 2], s[8 * ks + 3]);
            unsigned b0 = pkbf(s[8 * ks + 4], s[8 * ks + 5]);
            unsigned b1 = pkbf(s[8 * ks + 6], s[8 * ks + 7]);
            asm volatile("v_permlane32_swap_b32 %0, %1" : "+v"(a0), "+v"(b0));
            asm volatile("v_permlane32_swap_b32 %0, %1" : "+v"(a1), "+v"(b1));
            union { unsigned u[4]; bf16x8 v; } fr;
            fr.u[0] = a0; fr.u[1] = a1; fr.u[2] = b0; fr.u[3] = b1;
            pf[ks] = fr.v;
        }

        // ---- O^T += V^T P^T (V^T frags from swizzled private LDS) ----
        #pragma unroll
        for (int dt = 0; dt < 2; ++dt)
            #pragma unroll
            for (int ks = 0; ks < 2; ++ks) {
                const int ch = (ks * 2 + hi) ^ sw3;
                const bf16x8 vf = *(const bf16x8*)&Vs[(dt * 32 + l31) * 32 + ch * 8];
                acc[dt] = __builtin_amdgcn_mfma_f32_32x32x16_bf16(vf, pf[ks], acc[dt], 0, 0, 0);
            }
    }

    // ---- epilogue: normalize, per-wave LDS transpose O^T -> O rows, coalesced store ----
    unsigned short* ot = wb;   // reuse wave-private region (all staging drained: vmcnt(0))
    const float inv = 1.0f / lrun;
    #pragma unroll
    for (int g = 0; g < 4; g++) {
        ushort4 wa, wbv;
        wa.x = f2bf(acc[0][4 * g + 0] * inv); wa.y = f2bf(acc[0][4 * g + 1] * inv);
        wa.z = f2bf(acc[0][4 * g + 2] * inv); wa.w = f2bf(acc[0][4 * g + 3] * inv);
        wbv.x = f2bf(acc[1][4 * g + 0] * inv); wbv.y = f2bf(acc[1][4 * g + 1] * inv);
        wbv.z = f2bf(acc[1][4 * g + 2] * inv); wbv.w = f2bf(acc[1][4 * g + 3] * inv);
        *(ushort4*)&ot[l31 * 72 + 8 * g + 4 * hi] = wa;        // d-tile 0: d = 8g+4hi+e
        *(ushort4*)&ot[l31 * 72 + 32 + 8 * g + 4 * hi] = wbv;  // d-tile 1
    }
    __syncthreads();   // same-wave write->read ordering (executed once by every wave)
    const int b = bh >> 4, h = bh & 15;
    #pragma unroll
    for (int pss = 0; pss < 4; pss++) {
        const int q = pss * 8 + (lane >> 3);
        const uint4 val = *(const uint4*)&ot[q * 72 + (lane & 7) * 8];
        *(uint4*)&O[((size_t)(b * T_SZ + qw + q)) * C_SZ + h * D_SZ + (lane & 7) * 8] = val;
    }
}

// ---------------- launch ----------------

extern "C" void kernel_launch(void* const* d_in, const int* in_sizes, int n_in,
                              void* d_out, int out_size, void* d_ws, size_t ws_size,
                              hipStream_t stream)
{
    const float* x  = (const float*)d_in[0];
    const float* Wq = (const float*)d_in[1];
    const float* bq = (const float*)d_in[2];
    const float* Wk = (const float*)d_in[3];
    const float* bk = (const float*)d_in[4];
    const float* Wv = (const float*)d_in[5];
    const float* bv = (const float*)d_in[6];
    const float* Wo = (const float*)d_in[7];
    const float* bo = (const float*)d_in[8];

    uint8_t* ws = (uint8_t*)d_ws;
    unsigned short* XB   = (unsigned short*)(ws);                        // 8 MB
    unsigned short* WT   = (unsigned short*)(ws + (8u  << 20));          // 8 MB (q,k,v,o)
    unsigned short* QKV  = (unsigned short*)(ws + (16u << 20));          // Q, K, V^T (24 MB)
    unsigned short* Vtmp = (unsigned short*)(ws + (40u << 20));          // V staging, then attn O

    cvt_x_kernel<<<2048, 256, 0, stream>>>((const float4*)x, (ushort4*)XB, M_SZ * C_SZ / 4);
    transpose_cvt_kernel<<<dim3(32, 32, 4), dim3(32, 8), 0, stream>>>(
        Wq, Wk, Wv, Wo, WT, WT + CC, WT + 2 * (size_t)CC, WT + 3 * (size_t)CC);
    gemm_qkv_kernel<<<dim3(24, 32), 256, 0, stream>>>(XB, WT, bq, bk, bv, QKV, Vtmp);
    vt_kernel<<<dim3(64, 2, 32), dim3(32, 8), 0, stream>>>(Vtmp, QKV + 2 * (size_t)BHTD);
    attn_fwd_kernel<<<512, 256, 0, stream>>>(
        QKV, QKV + BHTD, QKV + 2 * (size_t)BHTD, Vtmp);
    gemm_out_kernel<<<dim3(8, 64), 256, 0, stream>>>(Vtmp, WT + 3 * (size_t)CC, bo, (float*)d_out);
}

// Round 12
// 135.661 us; speedup vs baseline: 1.0547x; 1.0547x over previous
//
#include <hip/hip_runtime.h>
#include <stdint.h>
#include <stddef.h>

// Causal attention fused layer for MI355X (gfx950).
// B=2 T=2048 C=1024 H=16 D=64.
// Pipeline: cvt x -> bf16 | transpose-cvt weights -> bf16 N*K
//           | fused QKV GEMM (1 dispatch; V^T written via in-kernel LDS transpose)
//           | flash attention (R8 structure: swapped QK^T, 4-wave shared-staging blocks,
//             TRIPLE-buffered 64-kv LDS tiles, counted vmcnt(8), XOR-swizzle)
//           | out GEMM f32 (64x128 tiles, 512 blocks).
// Workspace layout (needs >= 48 MB):
//   [0,8MB)   x bf16            (M=4096 x K=1024)
//   [8,16MB)  Wt q,k,v,o bf16   (4 x 1024x1024, transposed N x K)
//   [16,32MB) Q,K bf16          ((B,H,T,D)), Q pre-scaled by 0.125*log2(e)
//   [32,40MB) V^T bf16          ((B,H,D,T), written directly by gemm_qkv epilogue)
//   [40,48MB) attn O bf16       ((B,T,C))

#define B_SZ 2
#define T_SZ 2048
#define C_SZ 1024
#define H_SZ 16
#define D_SZ 64
#define M_SZ (B_SZ * T_SZ)              // 4096
#define BHTD (B_SZ * H_SZ * T_SZ * D_SZ) // 4194304
#define CC (C_SZ * C_SZ)                 // 1048576

typedef __attribute__((ext_vector_type(8))) __bf16 bf16x8;
typedef __attribute__((ext_vector_type(4))) float f32x4;
typedef __attribute__((ext_vector_type(16))) float f32x16;

__device__ __forceinline__ unsigned short f2bf(float f) {
    union { float f; unsigned u; } v; v.f = f;
    v.u += 0x7fffu + ((v.u >> 16) & 1u);   // round-to-nearest-even
    return (unsigned short)(v.u >> 16);
}

__device__ __forceinline__ unsigned pkbf(float lo, float hi_) {
    union { unsigned u; __bf16 h[2]; } r;
    r.h[0] = (__bf16)lo; r.h[1] = (__bf16)hi_;    // compiler emits v_cvt_pk_bf16_f32
    return r.u;
}

__device__ __forceinline__ void load_lds16(const unsigned short* g, unsigned short* l) {
    __builtin_amdgcn_global_load_lds(
        (const __attribute__((address_space(1))) void*)g,
        (__attribute__((address_space(3))) void*)l, 16, 0, 0);
}

// ---------------- conversion kernels ----------------

__global__ void cvt_x_kernel(const float4* __restrict__ in, ushort4* __restrict__ out, int n4) {
    int stride = gridDim.x * blockDim.x;
    for (int i = blockIdx.x * blockDim.x + threadIdx.x; i < n4; i += stride) {
        float4 v = in[i];
        ushort4 o;
        o.x = f2bf(v.x); o.y = f2bf(v.y); o.z = f2bf(v.z); o.w = f2bf(v.w);
        out[i] = o;
    }
}

__global__ __launch_bounds__(256) void transpose_cvt_kernel(
    const float* __restrict__ W0, const float* __restrict__ W1,
    const float* __restrict__ W2, const float* __restrict__ W3,
    unsigned short* __restrict__ T0, unsigned short* __restrict__ T1,
    unsigned short* __restrict__ T2, unsigned short* __restrict__ T3)
{
    __shared__ float tile[32][33];
    const float* W; unsigned short* Wt;
    switch (blockIdx.z) {
        case 0: W = W0; Wt = T0; break;
        case 1: W = W1; Wt = T1; break;
        case 2: W = W2; Wt = T2; break;
        default: W = W3; Wt = T3; break;
    }
    const int tx = threadIdx.x, ty = threadIdx.y;     // 32 x 8
    const int n0 = blockIdx.x * 32, k0 = blockIdx.y * 32;
    #pragma unroll
    for (int i = 0; i < 4; i++)
        tile[ty + i * 8][tx] = W[(size_t)(k0 + ty + i * 8) * C_SZ + n0 + tx];
    __syncthreads();
    #pragma unroll
    for (int i = 0; i < 4; i++)
        Wt[(size_t)(n0 + ty + i * 8) * C_SZ + k0 + tx] = f2bf(tile[tx][ty + i * 8]);
}

// ---------------- GEMM core (m97 structure: 128x128 tile, BK=32) ----------------

__device__ __forceinline__ void gemm_tile_core(
    const unsigned short* __restrict__ A,
    const unsigned short* __restrict__ Bt,
    unsigned short* As, unsigned short* Bs,
    int m0, int n0, f32x4 acc[4][4])
{
    const int tid = threadIdx.x;
    const int lane = tid & 63;
    const int w = tid >> 6;
    const int l15 = lane & 15, lg = lane >> 4;
    const int wr = (w >> 1) * 64, wc = (w & 1) * 64;

    const unsigned short* Ag0 = A + (size_t)(m0 + (tid >> 2)) * C_SZ + (tid & 3) * 8;
    const unsigned short* Ag1 = Ag0 + (size_t)64 * C_SZ;
    const unsigned short* Bg0 = Bt + (size_t)(n0 + (tid >> 2)) * C_SZ + (tid & 3) * 8;
    const unsigned short* Bg1 = Bg0 + (size_t)64 * C_SZ;
    unsigned short* As0 = As + w * 512;
    unsigned short* As1 = As + 2048 + w * 512;
    unsigned short* Bs0 = Bs + w * 512;
    unsigned short* Bs1 = Bs + 2048 + w * 512;

    for (int k0 = 0; k0 < C_SZ; k0 += 32) {
        load_lds16(Ag0 + k0, As0);
        load_lds16(Ag1 + k0, As1);
        load_lds16(Bg0 + k0, Bs0);
        load_lds16(Bg1 + k0, Bs1);
        __syncthreads();
        bf16x8 af[4], bfv[4];
        const bf16x8* Ap = (const bf16x8*)As;
        const bf16x8* Bp = (const bf16x8*)Bs;
        #pragma unroll
        for (int m = 0; m < 4; m++) af[m] = Ap[(wr + m * 16 + l15) * 4 + lg];
        #pragma unroll
        for (int n = 0; n < 4; n++) bfv[n] = Bp[(wc + n * 16 + l15) * 4 + lg];
        #pragma unroll
        for (int m = 0; m < 4; m++)
            #pragma unroll
            for (int n = 0; n < 4; n++)
                acc[m][n] = __builtin_amdgcn_mfma_f32_16x16x32_bf16(af[m], bfv[n], acc[m][n], 0, 0, 0);
        __syncthreads();
    }
}

// Fused QKV projection GEMM: ONE dispatch, grid (24, 32); z = blockIdx.x>>3 selects Q/K/V,
// n0 = (blockIdx.x&7)*128. Q,K -> (B,H,T,D) bf16 (Q scaled by 0.125*log2(e)).
// V -> (B,H,D,T) DIRECTLY via 128x128 LDS transpose epilogue (coalesced 256B row stores);
// this replaces the separate vt_kernel.
__global__ __launch_bounds__(256) void gemm_qkv_kernel(
    const unsigned short* __restrict__ A,
    const unsigned short* __restrict__ WtBase,
    const float* __restrict__ bq, const float* __restrict__ bk, const float* __restrict__ bv,
    unsigned short* __restrict__ QKV)
{
    __shared__ __align__(16) unsigned short smem[17408];   // core: As[0,4096)+Bs[4096,8192); V^T epi: 128x136
    unsigned short* As = smem;
    unsigned short* Bs = smem + 4096;
    const int z = blockIdx.x >> 3;
    const unsigned short* Bt = WtBase + (size_t)z * CC;
    const float* bias = (z == 0) ? bq : (z == 1) ? bk : bv;
    const float scale = (z == 0) ? 0.18033688011112042f : 1.0f;  // 0.125 * log2(e)
    unsigned short* Out = QKV + (size_t)z * BHTD;

    f32x4 acc[4][4];
    f32x4 zero4 = {0.f, 0.f, 0.f, 0.f};
    #pragma unroll
    for (int m = 0; m < 4; m++)
        #pragma unroll
        for (int n = 0; n < 4; n++) acc[m][n] = zero4;

    const int m0 = blockIdx.y * 128, n0 = (blockIdx.x & 7) * 128;
    gemm_tile_core(A, Bt, As, Bs, m0, n0, acc);

    const int lane = threadIdx.x & 63;
    const int w = threadIdx.x >> 6;
    const int l15 = lane & 15, lg = lane >> 4;
    const int wr = (w >> 1) * 64, wc = (w & 1) * 64;
    if (z == 2) {
        // V^T epilogue: acc(t,d) -> LDS transposed ot[d'][t'] (stride 136) -> coalesced rows.
        unsigned short* ot = smem;   // 128 x 136 ushorts (core LDS dead after final sync)
        #pragma unroll
        for (int n = 0; n < 4; n++) {
            const int dp = wc + n * 16 + l15;            // block-local d' 0..127
            const float bias_v = bias[n0 + dp];
            #pragma unroll
            for (int m = 0; m < 4; m++)
                #pragma unroll
                for (int j = 0; j < 4; j++)
                    ot[dp * 136 + wr + m * 16 + lg * 4 + j] = f2bf(acc[m][n][j] + bias_v);
        }
        __syncthreads();
        const int b = m0 >> 11, t0 = m0 & (T_SZ - 1);
        const int tid = threadIdx.x;
        #pragma unroll
        for (int k = 0; k < 8; k++) {
            const int c = tid + k * 256;                 // 0..2047 chunk id
            const int dp = c >> 4, tc = c & 15;
            const int col = n0 + dp;
            const int h = col >> 6, d = col & 63;
            const uint4 val = *(const uint4*)&ot[dp * 136 + tc * 8];
            *(uint4*)&Out[(((size_t)(b * H_SZ + h)) * D_SZ + d) * T_SZ + t0 + tc * 8] = val;
        }
    } else {
        #pragma unroll
        for (int n = 0; n < 4; n++) {
            const int col = n0 + wc + n * 16 + l15;
            const float bias_v = bias[col];
            const int h = col >> 6, d = col & 63;
            #pragma unroll
            for (int m = 0; m < 4; m++) {
                #pragma unroll
                for (int j = 0; j < 4; j++) {
                    const int row = m0 + wr + m * 16 + lg * 4 + j;   // global M row = b*T + t
                    const int b = row >> 11, t = row & (T_SZ - 1);
                    Out[(((size_t)(b * H_SZ + h)) * T_SZ + t) * D_SZ + d] =
                        f2bf((acc[m][n][j] + bias_v) * scale);
                }
            }
        }
    }
}

// Output projection GEMM: 64x128 tiles (grid 8 x 64 = 512 blocks -> 2 blocks/CU).
__global__ __launch_bounds__(256) void gemm_out_kernel(
    const unsigned short* __restrict__ A,
    const unsigned short* __restrict__ Bt,
    const float* __restrict__ bo,
    float* __restrict__ Out)
{
    __shared__ unsigned short As[2048], Bs[4096];
    const int tid = threadIdx.x;
    const int lane = tid & 63;
    const int w = tid >> 6;
    const int l15 = lane & 15, lg = lane >> 4;
    const int wc = w * 32;
    const int m0 = blockIdx.y * 64, n0 = blockIdx.x * 128;

    const unsigned short* Ag  = A + (size_t)(m0 + (tid >> 2)) * C_SZ + (tid & 3) * 8;
    const unsigned short* Bg0 = Bt + (size_t)(n0 + (tid >> 2)) * C_SZ + (tid & 3) * 8;
    const unsigned short* Bg1 = Bg0 + (size_t)64 * C_SZ;
    unsigned short* As0 = As + w * 512;
    unsigned short* Bs0 = Bs + w * 512;
    unsigned short* Bs1 = Bs + 2048 + w * 512;

    f32x4 acc[4][2];
    f32x4 zero4 = {0.f, 0.f, 0.f, 0.f};
    #pragma unroll
    for (int m = 0; m < 4; m++)
        #pragma unroll
        for (int n = 0; n < 2; n++) acc[m][n] = zero4;

    for (int k0 = 0; k0 < C_SZ; k0 += 32) {
        load_lds16(Ag + k0, As0);
        load_lds16(Bg0 + k0, Bs0);
        load_lds16(Bg1 + k0, Bs1);
        __syncthreads();
        bf16x8 af[4], bfv[2];
        const bf16x8* Ap = (const bf16x8*)As;
        const bf16x8* Bp = (const bf16x8*)Bs;
        #pragma unroll
        for (int m = 0; m < 4; m++) af[m] = Ap[(m * 16 + l15) * 4 + lg];
        #pragma unroll
        for (int n = 0; n < 2; n++) bfv[n] = Bp[(wc + n * 16 + l15) * 4 + lg];
        #pragma unroll
        for (int m = 0; m < 4; m++)
            #pragma unroll
            for (int n = 0; n < 2; n++)
                acc[m][n] = __builtin_amdgcn_mfma_f32_16x16x32_bf16(af[m], bfv[n], acc[m][n], 0, 0, 0);
        __syncthreads();
    }

    #pragma unroll
    for (int n = 0; n < 2; n++) {
        const int col = n0 + wc + n * 16 + l15;
        const float bias_v = bo[col];
        #pragma unroll
        for (int m = 0; m < 4; m++) {
            #pragma unroll
            for (int j = 0; j < 4; j++) {
                const int row = m0 + m * 16 + lg * 4 + j;
                Out[(size_t)row * C_SZ + col] = acc[m][n][j] + bias_v;
            }
        }
    }
}

// ---------------- flash attention (R8 structure + TRIPLE-buffered staging) ----------------
// grid 512 x 256thr (4 waves). qt pairing decode, bh = idx&31. Block owns 128 q rows
// (wave w: qw = qt*128 + 32w); all waves share staged 64-kv tiles (3 buffers x 16KB = 48KB).
// Pipeline: issue STAGE(t+2) -> s_waitcnt vmcnt(8) (tile t landed; t+1,t+2 in flight, 2-deep
// prefetch covers ~2 compute phases) -> s_barrier -> compute(t) -> s_barrier. Buffer hazard:
// compute reads buf[t%3]; stage targets buf[(t+2)%3] != t%3, != (t+1)%3; buf[t%3] re-staged
// only at iteration t+1 (after the trailing barrier of iteration t). vmcnt is per-wave; the
// pre-compute barrier converts each wave's own-loads-done into all-loads-done (as R7/R8).
// K/V^T staged via global_load_lds with pre-swizzled source (slot ^= row&7); ds_read applies
// the same XOR. Math (verified R3-R8): S^T = mfma(K,Q) 32x32x16 (C/D: col=lane&31,
// row=(r&3)+8*(r>>2)+4*(lane>>5)); in-register softmax at q=l31 (serial reduce, R8-exact);
// P^T via cvt_pk + v_permlane32_swap_b32; O^T += mfma(V^T, P^T); deferred-rescale THR=8.
__global__ __launch_bounds__(256) void attn_fwd_kernel(
    const unsigned short* __restrict__ Q,
    const unsigned short* __restrict__ K,
    const unsigned short* __restrict__ Vt,
    unsigned short* __restrict__ O)
{
    const int idx = blockIdx.x;
    const int qt = (idx < 256) ? (15 - (idx >> 5)) : ((idx - 256) >> 5);
    const int bh = idx & 31;
    const int w = threadIdx.x >> 6;
    const int lane = threadIdx.x & 63;
    const int l31 = lane & 31, hi = lane >> 5;
    const int qw = qt * 128 + 32 * w;

    const unsigned short* Qh = Q + (size_t)bh * T_SZ * D_SZ;
    const unsigned short* Kh = K + (size_t)bh * T_SZ * D_SZ;
    const unsigned short* Vh = Vt + (size_t)bh * T_SZ * D_SZ;   // (D,T) layout

    // triple buffer: buf b at smem + b*8192: K tile [0,4096), V^T tile [4096,8192) ushorts
    __shared__ __align__(16) unsigned short smem[24576];

    const int c0 = w * 64 + lane;
    const int row0 = c0 >> 3;
    const int sw0 = (c0 & 7) ^ (row0 & 7);
    const int koff0 = row0 * 64 + sw0 * 8;          // ushort offset in K tile source
    const int voff0 = row0 * T_SZ + sw0 * 8;        // ushort offset in V^T source (row stride T)
    const int ldsb0 = w * 512;                      // wave-uniform LDS dest base

    // Q B-frags: q = qw + l31, k-chunks j*16 + 8*hi
    bf16x8 qf[4];
    #pragma unroll
    for (int j = 0; j < 4; j++)
        qf[j] = *(const bf16x8*)&Qh[(size_t)(qw + l31) * D_SZ + j * 16 + 8 * hi];

    f32x16 acc[2];                 // O^T: d-tiles 0/1, q=l31 cols
    #pragma unroll
    for (int r = 0; r < 16; r++) { acc[0][r] = 0.f; acc[1][r] = 0.f; }
    float mrun = -3.0e38f, lrun = 0.f;

    const int tlast = (qw + 31) >> 6;
    const int ntb = 2 * qt + 2;    // >= 2 always
    const int qrow = qw + l31;
    const int swl = l31 & 7;

    // ---- prologue: stage tiles 0 and 1 (8 loads in flight) ----
    {
        load_lds16(Kh + koff0, smem + ldsb0);
        load_lds16(Kh + koff0 + 2048, smem + 2048 + ldsb0);
        load_lds16(Vh + voff0, smem + 4096 + ldsb0);
        load_lds16(Vh + voff0 + 32 * T_SZ, smem + 6144 + ldsb0);
        const unsigned short* Kt = Kh + (size_t)64 * D_SZ;
        const unsigned short* Vtt = Vh + 64;
        load_lds16(Kt + koff0, smem + 8192 + ldsb0);
        load_lds16(Kt + koff0 + 2048, smem + 10240 + ldsb0);
        load_lds16(Vtt + voff0, smem + 12288 + ldsb0);
        load_lds16(Vtt + voff0 + 32 * T_SZ, smem + 14336 + ldsb0);
    }

    for (int tt = 0; tt < ntb; ++tt) {
        // ---- issue staging for tile tt+2, then wait only for tile tt's loads ----
        if (tt + 2 < ntb) {
            unsigned short* Bd = smem + ((tt + 2) % 3) * 8192;
            const unsigned short* Kt = Kh + (size_t)(tt + 2) * 64 * D_SZ;
            const unsigned short* Vtt = Vh + (tt + 2) * 64;
            load_lds16(Kt + koff0, Bd + ldsb0);
            load_lds16(Kt + koff0 + 2048, Bd + 2048 + ldsb0);
            load_lds16(Vtt + voff0, Bd + 4096 + ldsb0);
            load_lds16(Vtt + voff0 + 32 * T_SZ, Bd + 6144 + ldsb0);
            asm volatile("s_waitcnt vmcnt(8)" ::: "memory");
        } else if (tt + 1 < ntb) {
            asm volatile("s_waitcnt vmcnt(4)" ::: "memory");
        } else {
            asm volatile("s_waitcnt vmcnt(0)" ::: "memory");
        }
        __builtin_amdgcn_s_barrier();   // tile tt visible to all waves

        if (tt <= tlast) {
            const unsigned short* Ks = smem + (tt % 3) * 8192;
            const unsigned short* Vs = Ks + 4096;
            const int k0 = tt * 64;

            // S^T = K Q^T (64kv x 32q) over D=64
            f32x16 s[2];
            #pragma unroll
            for (int kb = 0; kb < 2; ++kb) {
                bf16x8 kf[4];
                #pragma unroll
                for (int j = 0; j < 4; ++j) {
                    const int ch = (j * 2 + hi) ^ swl;
                    kf[j] = *(const bf16x8*)&Ks[(kb * 32 + l31) * 64 + ch * 8];
                }
                f32x16 sc;
                #pragma unroll
                for (int r = 0; r < 16; r++) sc[r] = 0.f;
                #pragma unroll
                for (int j = 0; j < 4; ++j)
                    sc = __builtin_amdgcn_mfma_f32_32x32x16_bf16(kf[j], qf[j], sc, 0, 0, 0);
                s[kb] = sc;
            }

            // causal mask (tiles overlapping this wave's diagonal)
            if (k0 + 63 > qw) {
                #pragma unroll
                for (int kb = 0; kb < 2; ++kb)
                    #pragma unroll
                    for (int r = 0; r < 16; ++r) {
                        const int kv = k0 + kb * 32 + (r & 3) + 8 * (r >> 2) + 4 * hi;
                        s[kb][r] = (kv > qrow) ? -3.0e38f : s[kb][r];
                    }
            }

            // in-register row max (per q=l31)
            float pm = s[0][0];
            #pragma unroll
            for (int r = 1; r < 16; r++) pm = fmaxf(pm, s[0][r]);
            #pragma unroll
            for (int r = 0; r < 16; r++) pm = fmaxf(pm, s[1][r]);
            pm = fmaxf(pm, __shfl_xor(pm, 32));

            // deferred-rescale (T13, THR=8 in log2 units)
            if (!__all(pm <= mrun + 8.0f)) {
                const float mnew = fmaxf(mrun, pm);
                const float al = exp2f(mrun - mnew);
                lrun *= al;
                #pragma unroll
                for (int r = 0; r < 16; r++) { acc[0][r] *= al; acc[1][r] *= al; }
                mrun = mnew;
            }

            // P = exp2(s - m), row sum
            float ps = 0.f;
            #pragma unroll
            for (int kb = 0; kb < 2; ++kb)
                #pragma unroll
                for (int r = 0; r < 16; r++) { s[kb][r] = exp2f(s[kb][r] - mrun); ps += s[kb][r]; }
            ps += __shfl_xor(ps, 32);
            lrun += ps;

            // pack P -> P^T B-frags via cvt_pk + permlane32_swap
            bf16x8 pf[2][2];
            #pragma unroll
            for (int kb = 0; kb < 2; ++kb) {
                #pragma unroll
                for (int ksl = 0; ksl < 2; ++ksl) {
                    unsigned a0 = pkbf(s[kb][8 * ksl + 0], s[kb][8 * ksl + 1]);
                    unsigned a1 = pkbf(s[kb][8 * ksl + 2], s[kb][8 * ksl + 3]);
                    unsigned b0 = pkbf(s[kb][8 * ksl + 4], s[kb][8 * ksl + 5]);
                    unsigned b1 = pkbf(s[kb][8 * ksl + 6], s[kb][8 * ksl + 7]);
                    asm volatile("v_permlane32_swap_b32 %0, %1" : "+v"(a0), "+v"(b0));
                    asm volatile("v_permlane32_swap_b32 %0, %1" : "+v"(a1), "+v"(b1));
                    union { unsigned u[4]; bf16x8 v; } fr;
                    fr.u[0] = a0; fr.u[1] = a1; fr.u[2] = b0; fr.u[3] = b1;
                    pf[kb][ksl] = fr.v;
                }
            }

            // O^T += V^T P^T (V^T frags from swizzled LDS)
            #pragma unroll
            for (int dt = 0; dt < 2; ++dt)
                #pragma unroll
                for (int kb = 0; kb < 2; ++kb)
                    #pragma unroll
                    for (int ksl = 0; ksl < 2; ++ksl) {
                        const int ks = kb * 2 + ksl;
                        const int ch = (ks * 2 + hi) ^ swl;
                        const bf16x8 vf = *(const bf16x8*)&Vs[(dt * 32 + l31) * 64 + ch * 8];
                        acc[dt] = __builtin_amdgcn_mfma_f32_32x32x16_bf16(vf, pf[kb][ksl], acc[dt], 0, 0, 0);
                    }
        }
        __builtin_amdgcn_s_barrier();   // all waves done reading buf[tt%3] before its re-stage
    }

    // ---- epilogue: normalize, per-wave LDS transpose O^T -> O rows, coalesced store ----
    unsigned short* ot = smem + w * 2304;   // 32 q rows x stride 72 (per-wave private)
    const float inv = 1.0f / lrun;
    #pragma unroll
    for (int g = 0; g < 4; g++) {
        ushort4 wa, wb;
        wa.x = f2bf(acc[0][4 * g + 0] * inv); wa.y = f2bf(acc[0][4 * g + 1] * inv);
        wa.z = f2bf(acc[0][4 * g + 2] * inv); wa.w = f2bf(acc[0][4 * g + 3] * inv);
        wb.x = f2bf(acc[1][4 * g + 0] * inv); wb.y = f2bf(acc[1][4 * g + 1] * inv);
        wb.z = f2bf(acc[1][4 * g + 2] * inv); wb.w = f2bf(acc[1][4 * g + 3] * inv);
        *(ushort4*)&ot[l31 * 72 + 8 * g + 4 * hi] = wa;        // d-tile 0: d = 8g+4hi+e
        *(ushort4*)&ot[l31 * 72 + 32 + 8 * g + 4 * hi] = wb;   // d-tile 1
    }
    const int b = bh >> 4, h = bh & 15;
    #pragma unroll
    for (int pss = 0; pss < 4; pss++) {
        const int q = pss * 8 + (lane >> 3);
        const uint4 val = *(const uint4*)&ot[q * 72 + (lane & 7) * 8];
        *(uint4*)&O[((size_t)(b * T_SZ + qw + q)) * C_SZ + h * D_SZ + (lane & 7) * 8] = val;
    }
}

// ---------------- launch ----------------

extern "C" void kernel_launch(void* const* d_in, const int* in_sizes, int n_in,
                              void* d_out, int out_size, void* d_ws, size_t ws_size,
                              hipStream_t stream)
{
    const float* x  = (const float*)d_in[0];
    const float* Wq = (const float*)d_in[1];
    const float* bq = (const float*)d_in[2];
    const float* Wk = (const float*)d_in[3];
    const float* bk = (const float*)d_in[4];
    const float* Wv = (const float*)d_in[5];
    const float* bv = (const float*)d_in[6];
    const float* Wo = (const float*)d_in[7];
    const float* bo = (const float*)d_in[8];

    uint8_t* ws = (uint8_t*)d_ws;
    unsigned short* XB  = (unsigned short*)(ws);                        // 8 MB
    unsigned short* WT  = (unsigned short*)(ws + (8u  << 20));          // 8 MB (q,k,v,o)
    unsigned short* QKV = (unsigned short*)(ws + (16u << 20));          // Q, K, V^T (24 MB)
    unsigned short* OB  = (unsigned short*)(ws + (40u << 20));          // attn O (8 MB)

    cvt_x_kernel<<<2048, 256, 0, stream>>>((const float4*)x, (ushort4*)XB, M_SZ * C_SZ / 4);
    transpose_cvt_kernel<<<dim3(32, 32, 4), dim3(32, 8), 0, stream>>>(
        Wq, Wk, Wv, Wo, WT, WT + CC, WT + 2 * (size_t)CC, WT + 3 * (size_t)CC);
    gemm_qkv_kernel<<<dim3(24, 32), 256, 0, stream>>>(XB, WT, bq, bk, bv, QKV);
    attn_fwd_kernel<<<512, 256, 0, stream>>>(
        QKV, QKV + BHTD, QKV + 2 * (size_t)BHTD, OB);
    gemm_out_kernel<<<dim3(8, 64), 256, 0, stream>>>(OB, WT + 3 * (size_t)CC, bo, (float*)d_out);
}

// Round 13
// 121.412 us; speedup vs baseline: 1.1785x; 1.1174x over previous
//
#include <hip/hip_runtime.h>
#include <stdint.h>
#include <stddef.h>

// Causal attention fused layer for MI355X (gfx950).
// B=2 T=2048 C=1024 H=16 D=64.
// Pipeline: cvt x -> bf16 | transpose-cvt weights -> bf16 N*K | fused QKV GEMM (1 dispatch)
//           | V transpose (B,H,D,T) | flash attention (swapped QK^T, 4-wave shared-staging,
//             triple-buffered 64-kv LDS tiles, counted vmcnt, XOR-swizzle, raw v_exp_f32,
//             4-way partial softmax reductions) | out GEMM f32 (64x128 tiles).
// Workspace layout (needs >= 48 MB):
//   [0,8MB)   x bf16            (M=4096 x K=1024)
//   [8,16MB)  Wt q,k,v,o bf16   (4 x 1024x1024, transposed N x K)
//   [16,32MB) Q,K bf16          ((B,H,T,D)), Q pre-scaled by 0.125*log2(e)
//   [32,40MB) V^T bf16          ((B,H,D,T))
//   [40,48MB) Vtmp then O bf16  (V normal layout, overwritten by attn output (B,T,C))

#define B_SZ 2
#define T_SZ 2048
#define C_SZ 1024
#define H_SZ 16
#define D_SZ 64
#define M_SZ (B_SZ * T_SZ)              // 4096
#define BHTD (B_SZ * H_SZ * T_SZ * D_SZ) // 4194304
#define CC (C_SZ * C_SZ)                 // 1048576

typedef __attribute__((ext_vector_type(8))) __bf16 bf16x8;
typedef __attribute__((ext_vector_type(4))) float f32x4;
typedef __attribute__((ext_vector_type(16))) float f32x16;

__device__ __forceinline__ unsigned short f2bf(float f) {
    union { float f; unsigned u; } v; v.f = f;
    v.u += 0x7fffu + ((v.u >> 16) & 1u);   // round-to-nearest-even
    return (unsigned short)(v.u >> 16);
}

__device__ __forceinline__ unsigned pkbf(float lo, float hi_) {
    union { unsigned u; __bf16 h[2]; } r;
    r.h[0] = (__bf16)lo; r.h[1] = (__bf16)hi_;    // compiler emits v_cvt_pk_bf16_f32
    return r.u;
}

// raw 2^x: single trans-pipe op (libm exp2f emits a ~6-op range-checked path).
// s_nop 0 covers the TRANS->VALU 1-wait-state hazard for the consumer.
// -3e38 input underflows to 0 (exactly what masked lanes need).
__device__ __forceinline__ float fexp2(float x) {
    float r;
    asm volatile("v_exp_f32 %0, %1\n\ts_nop 0" : "=v"(r) : "v"(x));
    return r;
}

__device__ __forceinline__ void load_lds16(const unsigned short* g, unsigned short* l) {
    __builtin_amdgcn_global_load_lds(
        (const __attribute__((address_space(1))) void*)g,
        (__attribute__((address_space(3))) void*)l, 16, 0, 0);
}

// ---------------- conversion kernels ----------------

__global__ void cvt_x_kernel(const float4* __restrict__ in, ushort4* __restrict__ out, int n4) {
    int stride = gridDim.x * blockDim.x;
    for (int i = blockIdx.x * blockDim.x + threadIdx.x; i < n4; i += stride) {
        float4 v = in[i];
        ushort4 o;
        o.x = f2bf(v.x); o.y = f2bf(v.y); o.z = f2bf(v.z); o.w = f2bf(v.w);
        out[i] = o;
    }
}

__global__ __launch_bounds__(256) void transpose_cvt_kernel(
    const float* __restrict__ W0, const float* __restrict__ W1,
    const float* __restrict__ W2, const float* __restrict__ W3,
    unsigned short* __restrict__ T0, unsigned short* __restrict__ T1,
    unsigned short* __restrict__ T2, unsigned short* __restrict__ T3)
{
    __shared__ float tile[32][33];
    const float* W; unsigned short* Wt;
    switch (blockIdx.z) {
        case 0: W = W0; Wt = T0; break;
        case 1: W = W1; Wt = T1; break;
        case 2: W = W2; Wt = T2; break;
        default: W = W3; Wt = T3; break;
    }
    const int tx = threadIdx.x, ty = threadIdx.y;     // 32 x 8
    const int n0 = blockIdx.x * 32, k0 = blockIdx.y * 32;
    #pragma unroll
    for (int i = 0; i < 4; i++)
        tile[ty + i * 8][tx] = W[(size_t)(k0 + ty + i * 8) * C_SZ + n0 + tx];
    __syncthreads();
    #pragma unroll
    for (int i = 0; i < 4; i++)
        Wt[(size_t)(n0 + ty + i * 8) * C_SZ + k0 + tx] = f2bf(tile[tx][ty + i * 8]);
}

// V (B,H,T,D) -> V^T (B,H,D,T), per-head 2048x64 transpose in 32x32 tiles.
__global__ __launch_bounds__(256) void vt_kernel(
    const unsigned short* __restrict__ V, unsigned short* __restrict__ Vt)
{
    __shared__ unsigned short tile[32][33];
    const int bh = blockIdx.z;
    const int t0 = blockIdx.x * 32, d0 = blockIdx.y * 32;
    const unsigned short* src = V + (size_t)bh * T_SZ * D_SZ;
    unsigned short* dst = Vt + (size_t)bh * T_SZ * D_SZ;
    const int tx = threadIdx.x, ty = threadIdx.y;     // 32 x 8
    #pragma unroll
    for (int i = 0; i < 4; i++)
        tile[ty + i * 8][tx] = src[(size_t)(t0 + ty + i * 8) * D_SZ + d0 + tx];
    __syncthreads();
    #pragma unroll
    for (int i = 0; i < 4; i++)
        dst[(size_t)(d0 + ty + i * 8) * T_SZ + t0 + tx] = tile[tx][ty + i * 8];
}

// ---------------- GEMM core (m97 structure: 128x128 tile, BK=32) ----------------

__device__ __forceinline__ void gemm_tile_core(
    const unsigned short* __restrict__ A,
    const unsigned short* __restrict__ Bt,
    unsigned short* As, unsigned short* Bs,
    int m0, int n0, f32x4 acc[4][4])
{
    const int tid = threadIdx.x;
    const int lane = tid & 63;
    const int w = tid >> 6;
    const int l15 = lane & 15, lg = lane >> 4;
    const int wr = (w >> 1) * 64, wc = (w & 1) * 64;

    const unsigned short* Ag0 = A + (size_t)(m0 + (tid >> 2)) * C_SZ + (tid & 3) * 8;
    const unsigned short* Ag1 = Ag0 + (size_t)64 * C_SZ;
    const unsigned short* Bg0 = Bt + (size_t)(n0 + (tid >> 2)) * C_SZ + (tid & 3) * 8;
    const unsigned short* Bg1 = Bg0 + (size_t)64 * C_SZ;
    unsigned short* As0 = As + w * 512;
    unsigned short* As1 = As + 2048 + w * 512;
    unsigned short* Bs0 = Bs + w * 512;
    unsigned short* Bs1 = Bs + 2048 + w * 512;

    for (int k0 = 0; k0 < C_SZ; k0 += 32) {
        load_lds16(Ag0 + k0, As0);
        load_lds16(Ag1 + k0, As1);
        load_lds16(Bg0 + k0, Bs0);
        load_lds16(Bg1 + k0, Bs1);
        __syncthreads();
        bf16x8 af[4], bfv[4];
        const bf16x8* Ap = (const bf16x8*)As;
        const bf16x8* Bp = (const bf16x8*)Bs;
        #pragma unroll
        for (int m = 0; m < 4; m++) af[m] = Ap[(wr + m * 16 + l15) * 4 + lg];
        #pragma unroll
        for (int n = 0; n < 4; n++) bfv[n] = Bp[(wc + n * 16 + l15) * 4 + lg];
        #pragma unroll
        for (int m = 0; m < 4; m++)
            #pragma unroll
            for (int n = 0; n < 4; n++)
                acc[m][n] = __builtin_amdgcn_mfma_f32_16x16x32_bf16(af[m], bfv[n], acc[m][n], 0, 0, 0);
        __syncthreads();
    }
}

// Fused QKV projection GEMM: ONE dispatch, grid (24, 32); z = blockIdx.x>>3 selects Q/K/V,
// n0 = (blockIdx.x&7)*128. Q,K -> (B,H,T,D) bf16 (Q scaled by 0.125*log2(e)); V -> Vtmp.
__global__ __launch_bounds__(256) void gemm_qkv_kernel(
    const unsigned short* __restrict__ A,
    const unsigned short* __restrict__ WtBase,
    const float* __restrict__ bq, const float* __restrict__ bk, const float* __restrict__ bv,
    unsigned short* __restrict__ QKV, unsigned short* __restrict__ Vtmp)
{
    __shared__ unsigned short As[4096], Bs[4096];
    const int z = blockIdx.x >> 3;
    const unsigned short* Bt = WtBase + (size_t)z * CC;
    const float* bias = (z == 0) ? bq : (z == 1) ? bk : bv;
    const float scale = (z == 0) ? 0.18033688011112042f : 1.0f;  // 0.125 * log2(e)
    unsigned short* Out = (z == 2) ? Vtmp : QKV + (size_t)z * BHTD;

    f32x4 acc[4][4];
    f32x4 zero4 = {0.f, 0.f, 0.f, 0.f};
    #pragma unroll
    for (int m = 0; m < 4; m++)
        #pragma unroll
        for (int n = 0; n < 4; n++) acc[m][n] = zero4;

    const int m0 = blockIdx.y * 128, n0 = (blockIdx.x & 7) * 128;
    gemm_tile_core(A, Bt, As, Bs, m0, n0, acc);

    const int lane = threadIdx.x & 63;
    const int w = threadIdx.x >> 6;
    const int l15 = lane & 15, lg = lane >> 4;
    const int wr = (w >> 1) * 64, wc = (w & 1) * 64;
    #pragma unroll
    for (int n = 0; n < 4; n++) {
        const int col = n0 + wc + n * 16 + l15;
        const float bias_v = bias[col];
        const int h = col >> 6, d = col & 63;
        #pragma unroll
        for (int m = 0; m < 4; m++) {
            #pragma unroll
            for (int j = 0; j < 4; j++) {
                const int row = m0 + wr + m * 16 + lg * 4 + j;   // global M row = b*T + t
                const int b = row >> 11, t = row & (T_SZ - 1);
                Out[(((size_t)(b * H_SZ + h)) * T_SZ + t) * D_SZ + d] =
                    f2bf((acc[m][n][j] + bias_v) * scale);
            }
        }
    }
}

// Output projection GEMM: 64x128 tiles (grid 8 x 64 = 512 blocks -> 2 blocks/CU).
__global__ __launch_bounds__(256) void gemm_out_kernel(
    const unsigned short* __restrict__ A,
    const unsigned short* __restrict__ Bt,
    const float* __restrict__ bo,
    float* __restrict__ Out)
{
    __shared__ unsigned short As[2048], Bs[4096];
    const int tid = threadIdx.x;
    const int lane = tid & 63;
    const int w = tid >> 6;
    const int l15 = lane & 15, lg = lane >> 4;
    const int wc = w * 32;
    const int m0 = blockIdx.y * 64, n0 = blockIdx.x * 128;

    const unsigned short* Ag  = A + (size_t)(m0 + (tid >> 2)) * C_SZ + (tid & 3) * 8;
    const unsigned short* Bg0 = Bt + (size_t)(n0 + (tid >> 2)) * C_SZ + (tid & 3) * 8;
    const unsigned short* Bg1 = Bg0 + (size_t)64 * C_SZ;
    unsigned short* As0 = As + w * 512;
    unsigned short* Bs0 = Bs + w * 512;
    unsigned short* Bs1 = Bs + 2048 + w * 512;

    f32x4 acc[4][2];
    f32x4 zero4 = {0.f, 0.f, 0.f, 0.f};
    #pragma unroll
    for (int m = 0; m < 4; m++)
        #pragma unroll
        for (int n = 0; n < 2; n++) acc[m][n] = zero4;

    for (int k0 = 0; k0 < C_SZ; k0 += 32) {
        load_lds16(Ag + k0, As0);
        load_lds16(Bg0 + k0, Bs0);
        load_lds16(Bg1 + k0, Bs1);
        __syncthreads();
        bf16x8 af[4], bfv[2];
        const bf16x8* Ap = (const bf16x8*)As;
        const bf16x8* Bp = (const bf16x8*)Bs;
        #pragma unroll
        for (int m = 0; m < 4; m++) af[m] = Ap[(m * 16 + l15) * 4 + lg];
        #pragma unroll
        for (int n = 0; n < 2; n++) bfv[n] = Bp[(wc + n * 16 + l15) * 4 + lg];
        #pragma unroll
        for (int m = 0; m < 4; m++)
            #pragma unroll
            for (int n = 0; n < 2; n++)
                acc[m][n] = __builtin_amdgcn_mfma_f32_16x16x32_bf16(af[m], bfv[n], acc[m][n], 0, 0, 0);
        __syncthreads();
    }

    #pragma unroll
    for (int n = 0; n < 2; n++) {
        const int col = n0 + wc + n * 16 + l15;
        const float bias_v = bo[col];
        #pragma unroll
        for (int m = 0; m < 4; m++) {
            #pragma unroll
            for (int j = 0; j < 4; j++) {
                const int row = m0 + m * 16 + lg * 4 + j;
                Out[(size_t)row * C_SZ + col] = acc[m][n][j] + bias_v;
            }
        }
    }
}

// ---------------- flash attention (triple-buffered, raw v_exp_f32) ----------------
// grid 512 x 256thr (4 waves). qt pairing decode, bh = idx&31. Block owns 128 q rows
// (wave w: qw = qt*128 + 32w); all waves share staged 64-kv tiles (3 buffers x 16KB = 48KB).
// Pipeline: issue STAGE(t+2) -> s_waitcnt vmcnt(8) (tile t landed; t+1,t+2 in flight) ->
// s_barrier -> compute(t) -> s_barrier. Buffer hazard: compute reads buf[t%3]; stage targets
// buf[(t+2)%3]; buf[t%3] re-staged only after iteration t's trailing barrier.
// K/V^T staged via global_load_lds with pre-swizzled source (slot ^= row&7); ds_read applies
// the same XOR. Math (verified R3-R12): S^T = mfma(K,Q) 32x32x16 (C/D: col=lane&31,
// row=(r&3)+8*(r>>2)+4*(lane>>5)); in-register softmax at q=l31 with 4-way partial max/sum
// (dep-chain 4x shorter) and raw v_exp_f32; P^T via cvt_pk + v_permlane32_swap_b32;
// O^T += mfma(V^T, P^T); deferred-rescale THR=8 (log2 units).
__global__ __launch_bounds__(256) void attn_fwd_kernel(
    const unsigned short* __restrict__ Q,
    const unsigned short* __restrict__ K,
    const unsigned short* __restrict__ Vt,
    unsigned short* __restrict__ O)
{
    const int idx = blockIdx.x;
    const int qt = (idx < 256) ? (15 - (idx >> 5)) : ((idx - 256) >> 5);
    const int bh = idx & 31;
    const int w = threadIdx.x >> 6;
    const int lane = threadIdx.x & 63;
    const int l31 = lane & 31, hi = lane >> 5;
    const int qw = qt * 128 + 32 * w;

    const unsigned short* Qh = Q + (size_t)bh * T_SZ * D_SZ;
    const unsigned short* Kh = K + (size_t)bh * T_SZ * D_SZ;
    const unsigned short* Vh = Vt + (size_t)bh * T_SZ * D_SZ;   // (D,T) layout

    // triple buffer: buf b at smem + b*8192: K tile [0,4096), V^T tile [4096,8192) ushorts
    __shared__ __align__(16) unsigned short smem[24576];

    const int c0 = w * 64 + lane;
    const int row0 = c0 >> 3;
    const int sw0 = (c0 & 7) ^ (row0 & 7);
    const int koff0 = row0 * 64 + sw0 * 8;          // ushort offset in K tile source
    const int voff0 = row0 * T_SZ + sw0 * 8;        // ushort offset in V^T source (row stride T)
    const int ldsb0 = w * 512;                      // wave-uniform LDS dest base

    // Q B-frags: q = qw + l31, k-chunks j*16 + 8*hi
    bf16x8 qf[4];
    #pragma unroll
    for (int j = 0; j < 4; j++)
        qf[j] = *(const bf16x8*)&Qh[(size_t)(qw + l31) * D_SZ + j * 16 + 8 * hi];

    f32x16 acc[2];                 // O^T: d-tiles 0/1, q=l31 cols
    #pragma unroll
    for (int r = 0; r < 16; r++) { acc[0][r] = 0.f; acc[1][r] = 0.f; }
    float mrun = -3.0e38f, lrun = 0.f;

    const int tlast = (qw + 31) >> 6;
    const int ntb = 2 * qt + 2;    // >= 2 always
    const int qrow = qw + l31;
    const int swl = l31 & 7;

    // ---- prologue: stage tiles 0 and 1 (8 loads in flight) ----
    {
        load_lds16(Kh + koff0, smem + ldsb0);
        load_lds16(Kh + koff0 + 2048, smem + 2048 + ldsb0);
        load_lds16(Vh + voff0, smem + 4096 + ldsb0);
        load_lds16(Vh + voff0 + 32 * T_SZ, smem + 6144 + ldsb0);
        const unsigned short* Kt = Kh + (size_t)64 * D_SZ;
        const unsigned short* Vtt = Vh + 64;
        load_lds16(Kt + koff0, smem + 8192 + ldsb0);
        load_lds16(Kt + koff0 + 2048, smem + 10240 + ldsb0);
        load_lds16(Vtt + voff0, smem + 12288 + ldsb0);
        load_lds16(Vtt + voff0 + 32 * T_SZ, smem + 14336 + ldsb0);
    }

    for (int tt = 0; tt < ntb; ++tt) {
        // ---- issue staging for tile tt+2, then wait only for tile tt's loads ----
        if (tt + 2 < ntb) {
            unsigned short* Bd = smem + ((tt + 2) % 3) * 8192;
            const unsigned short* Kt = Kh + (size_t)(tt + 2) * 64 * D_SZ;
            const unsigned short* Vtt = Vh + (tt + 2) * 64;
            load_lds16(Kt + koff0, Bd + ldsb0);
            load_lds16(Kt + koff0 + 2048, Bd + 2048 + ldsb0);
            load_lds16(Vtt + voff0, Bd + 4096 + ldsb0);
            load_lds16(Vtt + voff0 + 32 * T_SZ, Bd + 6144 + ldsb0);
            asm volatile("s_waitcnt vmcnt(8)" ::: "memory");
        } else if (tt + 1 < ntb) {
            asm volatile("s_waitcnt vmcnt(4)" ::: "memory");
        } else {
            asm volatile("s_waitcnt vmcnt(0)" ::: "memory");
        }
        __builtin_amdgcn_s_barrier();   // tile tt visible to all waves

        if (tt <= tlast) {
            const unsigned short* Ks = smem + (tt % 3) * 8192;
            const unsigned short* Vs = Ks + 4096;
            const int k0 = tt * 64;

            // S^T = K Q^T (64kv x 32q) over D=64
            f32x16 s[2];
            #pragma unroll
            for (int kb = 0; kb < 2; ++kb) {
                bf16x8 kf[4];
                #pragma unroll
                for (int j = 0; j < 4; ++j) {
                    const int ch = (j * 2 + hi) ^ swl;
                    kf[j] = *(const bf16x8*)&Ks[(kb * 32 + l31) * 64 + ch * 8];
                }
                f32x16 sc;
                #pragma unroll
                for (int r = 0; r < 16; r++) sc[r] = 0.f;
                #pragma unroll
                for (int j = 0; j < 4; ++j)
                    sc = __builtin_amdgcn_mfma_f32_32x32x16_bf16(kf[j], qf[j], sc, 0, 0, 0);
                s[kb] = sc;
            }

            // causal mask (tiles overlapping this wave's diagonal)
            if (k0 + 63 > qw) {
                #pragma unroll
                for (int kb = 0; kb < 2; ++kb)
                    #pragma unroll
                    for (int r = 0; r < 16; ++r) {
                        const int kv = k0 + kb * 32 + (r & 3) + 8 * (r >> 2) + 4 * hi;
                        s[kb][r] = (kv > qrow) ? -3.0e38f : s[kb][r];
                    }
            }

            // row max: 4 independent partial chains (dep depth 8) + combine
            float pm0 = fmaxf(s[0][0], s[1][0]), pm1 = fmaxf(s[0][1], s[1][1]);
            float pm2 = fmaxf(s[0][2], s[1][2]), pm3 = fmaxf(s[0][3], s[1][3]);
            #pragma unroll
            for (int r = 4; r < 16; r += 4) {
                pm0 = fmaxf(pm0, fmaxf(s[0][r + 0], s[1][r + 0]));
                pm1 = fmaxf(pm1, fmaxf(s[0][r + 1], s[1][r + 1]));
                pm2 = fmaxf(pm2, fmaxf(s[0][r + 2], s[1][r + 2]));
                pm3 = fmaxf(pm3, fmaxf(s[0][r + 3], s[1][r + 3]));
            }
            float pm = fmaxf(fmaxf(pm0, pm1), fmaxf(pm2, pm3));
            pm = fmaxf(pm, __shfl_xor(pm, 32));

            // deferred-rescale (T13, THR=8 in log2 units)
            if (!__all(pm <= mrun + 8.0f)) {
                const float mnew = fmaxf(mrun, pm);
                const float al = fexp2(mrun - mnew);
                lrun *= al;
                #pragma unroll
                for (int r = 0; r < 16; r++) { acc[0][r] *= al; acc[1][r] *= al; }
                mrun = mnew;
            }

            // P = exp2(s - m) via raw v_exp_f32; 4-way partial row sum
            #pragma unroll
            for (int kb = 0; kb < 2; ++kb)
                #pragma unroll
                for (int r = 0; r < 16; r++) s[kb][r] = fexp2(s[kb][r] - mrun);
            float ps0 = s[0][0] + s[1][0], ps1 = s[0][1] + s[1][1];
            float ps2 = s[0][2] + s[1][2], ps3 = s[0][3] + s[1][3];
            #pragma unroll
            for (int r = 4; r < 16; r += 4) {
                ps0 += s[0][r + 0] + s[1][r + 0];
                ps1 += s[0][r + 1] + s[1][r + 1];
                ps2 += s[0][r + 2] + s[1][r + 2];
                ps3 += s[0][r + 3] + s[1][r + 3];
            }
            float ps = (ps0 + ps1) + (ps2 + ps3);
            ps += __shfl_xor(ps, 32);
            lrun += ps;

            // pack P -> P^T B-frags via cvt_pk + permlane32_swap
            bf16x8 pf[2][2];
            #pragma unroll
            for (int kb = 0; kb < 2; ++kb) {
                #pragma unroll
                for (int ksl = 0; ksl < 2; ++ksl) {
                    unsigned a0 = pkbf(s[kb][8 * ksl + 0], s[kb][8 * ksl + 1]);
                    unsigned a1 = pkbf(s[kb][8 * ksl + 2], s[kb][8 * ksl + 3]);
                    unsigned b0 = pkbf(s[kb][8 * ksl + 4], s[kb][8 * ksl + 5]);
                    unsigned b1 = pkbf(s[kb][8 * ksl + 6], s[kb][8 * ksl + 7]);
                    asm volatile("v_permlane32_swap_b32 %0, %1" : "+v"(a0), "+v"(b0));
                    asm volatile("v_permlane32_swap_b32 %0, %1" : "+v"(a1), "+v"(b1));
                    union { unsigned u[4]; bf16x8 v; } fr;
                    fr.u[0] = a0; fr.u[1] = a1; fr.u[2] = b0; fr.u[3] = b1;
                    pf[kb][ksl] = fr.v;
                }
            }

            // O^T += V^T P^T (V^T frags from swizzled LDS)
            #pragma unroll
            for (int dt = 0; dt < 2; ++dt)
                #pragma unroll
                for (int kb = 0; kb < 2; ++kb)
                    #pragma unroll
                    for (int ksl = 0; ksl < 2; ++ksl) {
                        const int ks = kb * 2 + ksl;
                        const int ch = (ks * 2 + hi) ^ swl;
                        const bf16x8 vf = *(const bf16x8*)&Vs[(dt * 32 + l31) * 64 + ch * 8];
                        acc[dt] = __builtin_amdgcn_mfma_f32_32x32x16_bf16(vf, pf[kb][ksl], acc[dt], 0, 0, 0);
                    }
        }
        __builtin_amdgcn_s_barrier();   // all waves done reading buf[tt%3] before its re-stage
    }

    // ---- epilogue: normalize, per-wave LDS transpose O^T -> O rows, coalesced store ----
    unsigned short* ot = smem + w * 2304;   // 32 q rows x stride 72 (per-wave private)
    const float inv = 1.0f / lrun;
    #pragma unroll
    for (int g = 0; g < 4; g++) {
        ushort4 wa, wb;
        wa.x = f2bf(acc[0][4 * g + 0] * inv); wa.y = f2bf(acc[0][4 * g + 1] * inv);
        wa.z = f2bf(acc[0][4 * g + 2] * inv); wa.w = f2bf(acc[0][4 * g + 3] * inv);
        wb.x = f2bf(acc[1][4 * g + 0] * inv); wb.y = f2bf(acc[1][4 * g + 1] * inv);
        wb.z = f2bf(acc[1][4 * g + 2] * inv); wb.w = f2bf(acc[1][4 * g + 3] * inv);
        *(ushort4*)&ot[l31 * 72 + 8 * g + 4 * hi] = wa;        // d-tile 0: d = 8g+4hi+e
        *(ushort4*)&ot[l31 * 72 + 32 + 8 * g + 4 * hi] = wb;   // d-tile 1
    }
    const int b = bh >> 4, h = bh & 15;
    #pragma unroll
    for (int pss = 0; pss < 4; pss++) {
        const int q = pss * 8 + (lane >> 3);
        const uint4 val = *(const uint4*)&ot[q * 72 + (lane & 7) * 8];
        *(uint4*)&O[((size_t)(b * T_SZ + qw + q)) * C_SZ + h * D_SZ + (lane & 7) * 8] = val;
    }
}

// ---------------- launch ----------------

extern "C" void kernel_launch(void* const* d_in, const int* in_sizes, int n_in,
                              void* d_out, int out_size, void* d_ws, size_t ws_size,
                              hipStream_t stream)
{
    const float* x  = (const float*)d_in[0];
    const float* Wq = (const float*)d_in[1];
    const float* bq = (const float*)d_in[2];
    const float* Wk = (const float*)d_in[3];
    const float* bk = (const float*)d_in[4];
    const float* Wv = (const float*)d_in[5];
    const float* bv = (const float*)d_in[6];
    const float* Wo = (const float*)d_in[7];
    const float* bo = (const float*)d_in[8];

    uint8_t* ws = (uint8_t*)d_ws;
    unsigned short* XB   = (unsigned short*)(ws);                        // 8 MB
    unsigned short* WT   = (unsigned short*)(ws + (8u  << 20));          // 8 MB (q,k,v,o)
    unsigned short* QKV  = (unsigned short*)(ws + (16u << 20));          // Q, K, V^T (24 MB)
    unsigned short* Vtmp = (unsigned short*)(ws + (40u << 20));          // V staging, then attn O

    cvt_x_kernel<<<2048, 256, 0, stream>>>((const float4*)x, (ushort4*)XB, M_SZ * C_SZ / 4);
    transpose_cvt_kernel<<<dim3(32, 32, 4), dim3(32, 8), 0, stream>>>(
        Wq, Wk, Wv, Wo, WT, WT + CC, WT + 2 * (size_t)CC, WT + 3 * (size_t)CC);
    gemm_qkv_kernel<<<dim3(24, 32), 256, 0, stream>>>(XB, WT, bq, bk, bv, QKV, Vtmp);
    vt_kernel<<<dim3(64, 2, 32), dim3(32, 8), 0, stream>>>(Vtmp, QKV + 2 * (size_t)BHTD);
    attn_fwd_kernel<<<512, 256, 0, stream>>>(
        QKV, QKV + BHTD, QKV + 2 * (size_t)BHTD, Vtmp);
    gemm_out_kernel<<<dim3(8, 64), 256, 0, stream>>>(Vtmp, WT + 3 * (size_t)CC, bo, (float*)d_out);
}